// Round 11
// baseline (669.436 us; speedup 1.0000x reference)
//
#include <hip/hip_runtime.h>

// Problem constants
#define BB 32
#define NN 2048
#define FF 3
#define HH 64
#define OUTC 128
#define KK 16
#define BN (BB * NN)   // 65536 points

typedef __attribute__((ext_vector_type(8))) __bf16 bf16x8;
typedef __attribute__((ext_vector_type(4))) float f32x4;

// Pack d2 + candidate index into one sortable u32:
// high 21 bits = monotone(float d2) truncated, low 11 bits = idx (NN=2^11).
__device__ __forceinline__ unsigned int packkey(float d2, unsigned int m) {
    unsigned int bb = __builtin_bit_cast(unsigned int, d2);
    unsigned int msk = (unsigned int)((int)bb >> 31);
    unsigned int srt = bb ^ (msk | 0x80000000u);
    return (srt & 0xFFFFF800u) | m;
}

__device__ __forceinline__ void ce(unsigned int& a, unsigned int& b) {
    unsigned int lo = a < b ? a : b;
    unsigned int hi = a < b ? b : a;
    a = lo; b = hi;
}

// Sort 16 keys ascending — Batcher odd-even mergesort (63 CE, branchless).
__device__ __forceinline__ void sort16(unsigned int k[16]) {
#pragma unroll
    for (int p = 1; p < 16; p <<= 1)
#pragma unroll
        for (int q = p; q >= 1; q >>= 1)
#pragma unroll
            for (int j = q % p; j + q < 16; j += 2 * q)
#pragma unroll
                for (int i = 0; i < q; ++i) {
                    int x = i + j, y = i + j + q;
                    if (y < 16 && (x / (2 * p) == y / (2 * p))) ce(k[x], k[y]);
                }
}

// keys (sorted asc) <- lowest-16 of union(keys, nk), nk sorted asc.
__device__ __forceinline__ void merge16(unsigned int keys[16], const unsigned int nk[16]) {
    unsigned int t[16];
#pragma unroll
    for (int i = 0; i < 16; ++i) {
        unsigned int b = nk[15 - i];
        t[i] = keys[i] < b ? keys[i] : b;
    }
#pragma unroll
    for (int d = 8; d >= 1; d >>= 1)
#pragma unroll
        for (int i = 0; i < 16; ++i)
            if ((i & d) == 0) ce(t[i], t[i ^ d]);
#pragma unroll
    for (int i = 0; i < 16; ++i) keys[i] = t[i];
}

__device__ __forceinline__ unsigned short bfbits(float v) {
    return __builtin_bit_cast(unsigned short, (__bf16)v);
}

// ---------------------------------------------------------------------------
// pack3: blocks [0,1024) = layer-0 kNN filter (D=3, candidate sq inline);
//        blocks [1024, 1024+BN/4) = prep3 (P/Q GEMM for layer 0).
// ---------------------------------------------------------------------------
__global__ __launch_bounds__(256) void pack3_kernel(const float* __restrict__ x,
                                                    const float* __restrict__ w1,
                                                    const float* __restrict__ b1,
                                                    float* __restrict__ P,
                                                    float* __restrict__ Q,
                                                    unsigned short* __restrict__ idx32) {
    __shared__ float4 lds_c[256];
    __shared__ unsigned int Km[64 * 68];
    const int tid = threadIdx.x;

    if (blockIdx.x >= 1024) {
        // ---- prep3: P/Q for 4 rows ----
        const int h = tid & 63;
        const int pl = tid >> 6;
        const long p = (long)(blockIdx.x - 1024) * 4 + pl;
        const float* fp = x + p * 3;
        const float fv[3] = {fp[0], fp[1], fp[2]};
        float accp = 0.f, accq = 0.f;
#pragma unroll
        for (int d = 0; d < 3; ++d) {
            float wa = w1[d * HH + h];
            float wb = w1[(3 + d) * HH + h];
            accp = fmaf(fv[d], wa - wb, accp);
            accq = fmaf(fv[d], wb, accq);
        }
        P[p * HH + h] = accp + b1[h];
        Q[p * HH + h] = accq;
        return;
    }

    // ---- filter3: 64 rows x 2048 cands, XCD-pinned ----
    const int xcd = blockIdx.x & 7;
    const int ii = blockIdx.x >> 3;
    const int b = xcd + 8 * (ii >> 5);
    const int rg = ii & 31;
    const long pbase = (long)b * NN;
    const int r = tid >> 2, slot = tid & 3;
    const int row = rg * 64 + r;

    const float* rp = x + (pbase + row) * 3;
    const float xr0 = rp[0], xr1 = rp[1], xr2 = rp[2];

    unsigned int keys[KK];
#pragma unroll
    for (int j = 0; j < KK; ++j) keys[j] = 0xFFFFFFFFu;

    // preload tile 0 (sq inline)
    float c0, c1, c2, c3;
    {
        const float* cp = x + (pbase + tid) * 3;
        c0 = cp[0]; c1 = cp[1]; c2 = cp[2];
        c3 = c0 * c0 + c1 * c1 + c2 * c2;
    }

    for (int t = 0; t < NN / 256; ++t) {
        __syncthreads();
        lds_c[tid] = make_float4(c0, c1, c2, c3);
        __syncthreads();
        if (t < NN / 256 - 1) {
            const int m = (t + 1) * 256 + tid;
            const float* cp = x + (pbase + m) * 3;
            c0 = cp[0]; c1 = cp[1]; c2 = cp[2];
            c3 = c0 * c0 + c1 * c1 + c2 * c2;
        }
        const int cbase = slot * 64;
#pragma unroll
        for (int bb = 0; bb < 4; ++bb) {
            unsigned int nk[16];
#pragma unroll
            for (int cc = 0; cc < 16; ++cc) {
                float4 v = lds_c[cbase + bb * 16 + cc];
                float dot = fmaf(xr0, v.x, fmaf(xr1, v.y, xr2 * v.z));
                float d2 = fmaf(-2.0f, dot, v.w);   // row sq dropped (rank-invariant)
                nk[cc] = packkey(d2, (unsigned int)(t * 256 + cbase + bb * 16 + cc));
            }
            sort16(nk);
            merge16(keys, nk);
        }
    }

    {
        uint4* kw = (uint4*)&Km[r * 68 + slot * 16];
#pragma unroll
        for (int q = 0; q < 4; ++q)
            kw[q] = make_uint4(keys[4 * q], keys[4 * q + 1], keys[4 * q + 2], keys[4 * q + 3]);
    }
    __syncthreads();
    if (slot < 2) {
        const unsigned int* k0 = &Km[r * 68 + slot * 32];
        const unsigned int* k1 = k0 + 16;
        unsigned short ms[16];
#pragma unroll
        for (int j = 0; j < 16; ++j) {
            unsigned int a = k0[j], bv = k1[15 - j];
            ms[j] = (unsigned short)((a < bv ? a : bv) & 0x7FFu);
        }
        uint4* op = (uint4*)(idx32 + ((pbase + row) * 32 + slot * 16));
        op[0] = ((const uint4*)ms)[0];
        op[1] = ((const uint4*)ms)[1];
    }
}

// ---------------------------------------------------------------------------
// prep_pq64: pure P/Q GEMM. Block = 64 rows; weights in VGPRs; rows via LDS
// broadcast ds_read_b128; split accumulators.
// ---------------------------------------------------------------------------
__global__ __launch_bounds__(256) void prep_pq64_kernel(const float* __restrict__ feat,
                                                        const float* __restrict__ w1,
                                                        const float* __restrict__ b1,
                                                        float* __restrict__ P,
                                                        float* __restrict__ Q) {
    __shared__ float rows[64 * HH];   // 16 KB
    const int tid = threadIdx.x;
    const int h = tid & 63;
    const int wv = tid >> 6;
    const long row0 = (long)blockIdx.x * 64;

    float wdiff[64], wbv[64];
#pragma unroll
    for (int d = 0; d < 64; ++d) {
        float wa = w1[d * HH + h];
        float wb_ = w1[(HH + d) * HH + h];
        wdiff[d] = wa - wb_;
        wbv[d] = wb_;
    }
    const float bv = b1[h];

    {
        const float4* src = (const float4*)(feat + row0 * HH);
        float4* dst = (float4*)rows;
#pragma unroll
        for (int i = 0; i < 4; ++i) dst[tid + 256 * i] = src[tid + 256 * i];
    }
    __syncthreads();

    for (int r = wv * 16; r < wv * 16 + 16; ++r) {
        const long p = row0 + r;
        float ap0 = 0.f, ap1 = 0.f, aq0 = 0.f, aq1 = 0.f;
#pragma unroll
        for (int d4 = 0; d4 < 16; ++d4) {
            float4 fv = *(const float4*)&rows[r * HH + d4 * 4];   // uniform -> broadcast
            ap0 = fmaf(fv.x, wdiff[4 * d4 + 0], ap0);
            aq0 = fmaf(fv.x, wbv[4 * d4 + 0], aq0);
            ap1 = fmaf(fv.y, wdiff[4 * d4 + 1], ap1);
            aq1 = fmaf(fv.y, wbv[4 * d4 + 1], aq1);
            ap0 = fmaf(fv.z, wdiff[4 * d4 + 2], ap0);
            aq0 = fmaf(fv.z, wbv[4 * d4 + 2], aq0);
            ap1 = fmaf(fv.w, wdiff[4 * d4 + 3], ap1);
            aq1 = fmaf(fv.w, wbv[4 * d4 + 3], aq1);
        }
        P[p * HH + h] = (ap0 + ap1) + bv;
        Q[p * HH + h] = aq0 + aq1;
    }
}

// ---------------------------------------------------------------------------
// bf16-MFMA filter (D=64): fp32 staging with inline bf16 convert (no bf16
// mirror buffer). Register prefetch, XCD-pinned batches, u16 output.
// ---------------------------------------------------------------------------
#define APAD 80   // LDS row stride (bf16 elems)
#define DPAD 68   // key-tile stride (u32)

__global__ __launch_bounds__(256) void knn_filter_kernel(const float* __restrict__ feat,
                                                         const float* __restrict__ sq,
                                                         unsigned short* __restrict__ idx32) {
    __shared__ __align__(16) __bf16 Ab[64 * APAD];
    __shared__ __align__(16) __bf16 Bb[64 * APAD];
    __shared__ __align__(16) unsigned int Dt[64 * DPAD];
    __shared__ float SqC[64];

    const int tid = threadIdx.x;
    const int xcd = blockIdx.x & 7;
    const int ii = blockIdx.x >> 3;
    const int b = xcd + 8 * (ii >> 5);
    const int rg = ii & 31;
    const long pbase = (long)b * NN;
    const int row0 = rg * 64;

    // stage A (64 rows x 64 dims): fp32 load -> bf16 LDS
    {
        const float4* src = (const float4*)(feat + (pbase + row0) * 64);
#pragma unroll
        for (int it = 0; it < 4; ++it) {
            const int i = it * 256 + tid;
            float4 v = src[i];
            const int rw = i >> 4, col = (i & 15) * 4;
            unsigned short u[4] = {bfbits(v.x), bfbits(v.y), bfbits(v.z), bfbits(v.w)};
            *(uint2*)&Ab[rw * APAD + col] = *(const uint2*)u;
        }
    }
    __syncthreads();

    const int wv = tid >> 6, ln = tid & 63;
    const int n16 = ln & 15, quad = ln >> 4;
    bf16x8 af0, af1;
    {
        const __bf16* ap = &Ab[(wv * 16 + n16) * APAD + quad * 8];
        af0 = *(const bf16x8*)ap;
        af1 = *(const bf16x8*)(ap + 32);
    }

    const int r = tid >> 2, slot = tid & 3;
    unsigned int keys[KK];
#pragma unroll
    for (int j = 0; j < KK; ++j) keys[j] = 0xFFFFFFFFu;

    // preload tile 0 into registers
    float4 pv[4];
    float psq;
    {
        const float4* src = (const float4*)(feat + pbase * 64);
#pragma unroll
        for (int it = 0; it < 4; ++it) pv[it] = src[it * 256 + tid];
        psq = (tid < 64) ? sq[pbase + tid] : 0.f;
    }

    for (int t = 0; t < NN / 64; ++t) {
        // staged write (registers -> bf16 LDS)
#pragma unroll
        for (int it = 0; it < 4; ++it) {
            const int i = it * 256 + tid;
            const int rw = i >> 4, col = (i & 15) * 4;
            unsigned short u[4] = {bfbits(pv[it].x), bfbits(pv[it].y),
                                   bfbits(pv[it].z), bfbits(pv[it].w)};
            *(uint2*)&Bb[rw * APAD + col] = *(const uint2*)u;
        }
        if (tid < 64) SqC[tid] = psq;
        __syncthreads();   // barrier 1: Bb/SqC ready; prev selection done with Dt

        // MFMA phase
#pragma unroll
        for (int ct = 0; ct < 4; ++ct) {
            const __bf16* bp = &Bb[(ct * 16 + n16) * APAD + quad * 8];
            bf16x8 bf0 = *(const bf16x8*)bp;
            bf16x8 bf1 = *(const bf16x8*)(bp + 32);
            f32x4 acc = {0.f, 0.f, 0.f, 0.f};
            acc = __builtin_amdgcn_mfma_f32_16x16x32_bf16(af0, bf0, acc, 0, 0, 0);
            acc = __builtin_amdgcn_mfma_f32_16x16x32_bf16(af1, bf1, acc, 0, 0, 0);
            const int ccol = ct * 16 + n16;
            const float sqc = SqC[ccol];
            const unsigned int m = (unsigned int)(t * 64 + ccol);
#pragma unroll
            for (int rr = 0; rr < 4; ++rr) {
                const int rrow = wv * 16 + quad * 4 + rr;
                Dt[rrow * DPAD + ccol] = packkey(fmaf(-2.0f, acc[rr], sqc), m);
            }
        }
        __syncthreads();   // barrier 2: Dt ready, Bb reads done

        // prefetch next tile (hidden by selection)
        if (t < NN / 64 - 1) {
            const float4* src = (const float4*)(feat + (pbase + (long)(t + 1) * 64) * 64);
#pragma unroll
            for (int it = 0; it < 4; ++it) pv[it] = src[it * 256 + tid];
            if (tid < 64) psq = sq[pbase + (t + 1) * 64 + tid];
        }

        // selection
        {
            const uint4* kp = (const uint4*)&Dt[r * DPAD + slot * 16];
            unsigned int nk[16];
#pragma unroll
            for (int q = 0; q < 4; ++q) {
                uint4 kv = kp[q];
                nk[4 * q + 0] = kv.x; nk[4 * q + 1] = kv.y;
                nk[4 * q + 2] = kv.z; nk[4 * q + 3] = kv.w;
            }
            sort16(nk);
            merge16(keys, nk);
        }
    }

    __syncthreads();
    {
        uint4* kw = (uint4*)&Dt[r * DPAD + slot * 16];
#pragma unroll
        for (int q = 0; q < 4; ++q)
            kw[q] = make_uint4(keys[4 * q], keys[4 * q + 1], keys[4 * q + 2], keys[4 * q + 3]);
    }
    __syncthreads();
    if (slot < 2) {
        const unsigned int* k0 = &Dt[r * DPAD + slot * 32];
        const unsigned int* k1 = k0 + 16;
        unsigned short ms[16];
#pragma unroll
        for (int j = 0; j < 16; ++j) {
            unsigned int a = k0[j], bv = k1[15 - j];
            ms[j] = (unsigned short)((a < bv ? a : bv) & 0x7FFu);
        }
        uint4* op = (uint4*)(idx32 + ((pbase + row0 + r) * 32 + slot * 16));
        op[0] = ((const uint4*)ms)[0];
        op[1] = ((const uint4*)ms)[1];
    }
}

// ---------------------------------------------------------------------------
// rescore3: exact fp32 rescore (cand sq inline) + gather + MLP0 -> featA;
// tail writes next-layer sq (sqn). Block = 8 rows.
// ---------------------------------------------------------------------------
__global__ __launch_bounds__(256) void rescore3_kernel(const float* __restrict__ x,
                                                       const unsigned short* __restrict__ idx32,
                                                       const float* __restrict__ P,
                                                       const float* __restrict__ Q,
                                                       const float* __restrict__ wo,
                                                       const float* __restrict__ bo,
                                                       float* __restrict__ outf,
                                                       float* __restrict__ sqn) {
    __shared__ float rowf[8][3];
    __shared__ float Sc[8][32];
    __shared__ int Ji[8][32];
    __shared__ int Li[8][KK];
    __shared__ float Rl[8][HH];
    const int tid = threadIdx.x;
    const int w = tid >> 6, ln = tid & 63;
    const int rw = ln >> 5, c = ln & 31;
    const int xcd = blockIdx.x & 7;
    const int ii = blockIdx.x >> 3;
    const int batch = xcd + 8 * (ii >> 8);
    const int rb = ii & 255;
    const long pbase = (long)batch * NN;
    const long pblk = pbase + (long)rb * 8;
    const long p = pblk + w * 2 + rw;
    const int row_ = w * 2 + rw;

    for (int i = tid; i < 24; i += 256) rowf[i / 3][i % 3] = x[pblk * 3 + i];
    Ji[row_][c] = (int)idx32[p * 32 + c];
    __syncthreads();

    {
        const int jj = Ji[row_][c];
        const float* cp = x + (pbase + jj) * 3;
        const float c0 = cp[0], c1 = cp[1], c2 = cp[2];
        const float sqc = c0 * c0 + c1 * c1 + c2 * c2;
        float dot = fmaf(rowf[row_][0], c0, fmaf(rowf[row_][1], c1, rowf[row_][2] * c2));
        Sc[row_][c] = fmaf(-2.0f, dot, sqc);
    }
    __syncthreads();

    {
        const float score = Sc[row_][c];
        const int j = Ji[row_][c];
        int rank = 0;
#pragma unroll
        for (int m = 0; m < 32; ++m) {
            float dm = Sc[row_][m];
            int jm = Ji[row_][m];
            rank += (dm < score || (dm == score && jm < j)) ? 1 : 0;
        }
        if (rank < KK) Li[row_][rank] = j;
    }
    __syncthreads();

    const int h = tid & 63, pl = tid >> 6;
#pragma unroll
    for (int rr0 = 0; rr0 < 2; ++rr0) {
        const int rr = pl + rr0 * 4;
        const long pp = pblk + rr;
        const float Pv = P[pp * HH + h];
        float acc = 0.f;
#pragma unroll
        for (int k = 0; k < KK; ++k) {
            int j2 = Li[rr][k];
            acc += fmaxf(Pv + Q[(pbase + j2) * HH + h], 0.f);
        }
        Rl[rr][h] = acc * (1.f / KK);
    }
    __syncthreads();
#pragma unroll
    for (int rr0 = 0; rr0 < 2; ++rr0) {
        const int rr = pl + rr0 * 4;
        float o = bo[h];
#pragma unroll
        for (int l = 0; l < HH; ++l) o = fmaf(Rl[rr][l], wo[l * HH + h], o);
        outf[(pblk + rr) * HH + h] = o;
        float s2 = o * o;
        s2 += __shfl_xor(s2, 1);
        s2 += __shfl_xor(s2, 2);
        s2 += __shfl_xor(s2, 4);
        s2 += __shfl_xor(s2, 8);
        s2 += __shfl_xor(s2, 16);
        s2 += __shfl_xor(s2, 32);
        if (h == 0) sqn[pblk + rr] = s2;
    }
}

// ---------------------------------------------------------------------------
// rescore64<LAST>: exact fp32 rescore + gather + MLP. Block = 8 rows.
// !LAST: writes next-layer feat + sq. LAST: emits pool partials only.
// ---------------------------------------------------------------------------
template <bool LAST>
__global__ __launch_bounds__(256) void rescore64_kernel(const float* __restrict__ feat,
                                                        const float* __restrict__ sq,
                                                        const unsigned short* __restrict__ idx32,
                                                        const float* __restrict__ P,
                                                        const float* __restrict__ Q,
                                                        const float* __restrict__ wo,
                                                        const float* __restrict__ bo,
                                                        float* __restrict__ outf,
                                                        float* __restrict__ sqn,
                                                        float* __restrict__ ppb) {
    __shared__ float rowf[8][HH];
    __shared__ float Sc[8][32];
    __shared__ int Ji[8][32];
    __shared__ float Sq32[8][32];
    __shared__ int Li[8][KK];
    __shared__ float Rl[8][HH];
    __shared__ float Psum[4][HH];
    const int tid = threadIdx.x;
    const int w = tid >> 6, ln = tid & 63;
    const int rw = ln >> 5, c = ln & 31;
    const int xcd = blockIdx.x & 7;
    const int ii = blockIdx.x >> 3;
    const int batch = xcd + 8 * (ii >> 8);
    const int rb = ii & 255;
    const long pbase = (long)batch * NN;
    const long pblk = pbase + (long)rb * 8;
    const long p = pblk + w * 2 + rw;
    const int row_ = w * 2 + rw;

    for (int i = tid; i < 8 * HH; i += 256) rowf[i / HH][i % HH] = feat[pblk * HH + i];
    {
        const int j0 = (int)idx32[p * 32 + c];
        Ji[row_][c] = j0;
        Sq32[row_][c] = sq[pbase + j0];
    }
    __syncthreads();

    // gather + dot, coalescing-optimal: 4 consecutive lanes share a cand line
    {
        const int cg = ln >> 2, e = ln & 3;
#pragma unroll
        for (int rr = 0; rr < 2; ++rr) {
#pragma unroll
            for (int pp = 0; pp < 2; ++pp) {
                const int row = w * 2 + rr;
                const int cand = pp * 16 + cg;
                const int jj = Ji[row][cand];
                const float* cb = feat + (pbase + jj) * 64;
                float part = 0.f;
#pragma unroll
                for (int blk = 0; blk < 4; ++blk) {
                    float4 cv = *(const float4*)(cb + blk * 16 + e * 4);
                    float4 rv = *(const float4*)&rowf[row][blk * 16 + e * 4];
                    part = fmaf(rv.x, cv.x, part);
                    part = fmaf(rv.y, cv.y, part);
                    part = fmaf(rv.z, cv.z, part);
                    part = fmaf(rv.w, cv.w, part);
                }
                part += __shfl_xor(part, 1);
                part += __shfl_xor(part, 2);
                if (e == 0) Sc[row][cand] = fmaf(-2.0f, part, Sq32[row][cand]);
            }
        }
    }
    __syncthreads();

    {
        const float score = Sc[row_][c];
        const int j = Ji[row_][c];
        int rank = 0;
#pragma unroll
        for (int m = 0; m < 32; ++m) {
            float dm = Sc[row_][m];
            int jm = Ji[row_][m];
            rank += (dm < score || (dm == score && jm < j)) ? 1 : 0;
        }
        if (rank < KK) Li[row_][rank] = j;
    }
    __syncthreads();

    const int h = tid & 63, pl = tid >> 6;
#pragma unroll
    for (int rr0 = 0; rr0 < 2; ++rr0) {
        const int rr = pl + rr0 * 4;
        const long pp = pblk + rr;
        const float Pv = P[pp * HH + h];
        float acc = 0.f;
#pragma unroll
        for (int k = 0; k < KK; ++k) {
            int j2 = Li[rr][k];
            acc += fmaxf(Pv + Q[(pbase + j2) * HH + h], 0.f);
        }
        Rl[rr][h] = acc * (1.f / KK);
    }
    __syncthreads();

    float posum = 0.f;
#pragma unroll
    for (int rr0 = 0; rr0 < 2; ++rr0) {
        const int rr = pl + rr0 * 4;
        float o = bo[h];
#pragma unroll
        for (int l = 0; l < HH; ++l) o = fmaf(Rl[rr][l], wo[l * HH + h], o);
        if constexpr (!LAST) {
            outf[(pblk + rr) * HH + h] = o;
            float s2 = o * o;
            s2 += __shfl_xor(s2, 1);
            s2 += __shfl_xor(s2, 2);
            s2 += __shfl_xor(s2, 4);
            s2 += __shfl_xor(s2, 8);
            s2 += __shfl_xor(s2, 16);
            s2 += __shfl_xor(s2, 32);
            if (h == 0) sqn[pblk + rr] = s2;
        } else {
            posum += o;
        }
    }
    if constexpr (LAST) {
        Psum[pl][h] = posum;
        __syncthreads();
        if (tid < HH) {
            float t4 = Psum[0][tid] + Psum[1][tid] + Psum[2][tid] + Psum[3][tid];
            ppb[((long)batch * 256 + rb) * HH + tid] = t4;
        }
    }
}

// ---------------------------------------------------------------------------
// head: g[b] = (1/N) * sum of 256 pool partials; out = relu(g@fw1+fb1)@fw2+fb2
// ---------------------------------------------------------------------------
__global__ __launch_bounds__(256) void head_kernel(const float* __restrict__ ppb,
                                                   const float* __restrict__ fw1,
                                                   const float* __restrict__ fb1,
                                                   const float* __restrict__ fw2,
                                                   const float* __restrict__ fb2,
                                                   float* __restrict__ out) {
    __shared__ float part[4][HH];
    __shared__ float g[HH];
    __shared__ float tl[HH];
    const int b = blockIdx.x;
    const int tid = threadIdx.x;
    const int h = tid & 63;
    const int ck = tid >> 6;
    float s = 0.f;
    for (int i = ck; i < 256; i += 4) s += ppb[((long)b * 256 + i) * HH + h];
    part[ck][h] = s;
    __syncthreads();
    if (tid < HH) g[tid] = (part[0][tid] + part[1][tid] + part[2][tid] + part[3][tid]) * (1.f / NN);
    __syncthreads();
    if (tid < HH) {
        float a = fb1[tid];
#pragma unroll
        for (int l = 0; l < HH; ++l) a = fmaf(g[l], fw1[l * HH + tid], a);
        tl[tid] = fmaxf(a, 0.f);
    }
    __syncthreads();
    if (tid < OUTC) {
        float o = fb2[tid];
#pragma unroll
        for (int l = 0; l < HH; ++l) o = fmaf(tl[l], fw2[l * OUTC + tid], o);
        out[(long)b * OUTC + tid] = o;
    }
}

// ---------------------------------------------------------------------------
extern "C" void kernel_launch(void* const* d_in, const int* in_sizes, int n_in,
                              void* d_out, int out_size, void* d_ws, size_t ws_size,
                              hipStream_t stream) {
    const float* x    = (const float*)d_in[0];
    const float* w1_0 = (const float*)d_in[1];
    const float* b1_0 = (const float*)d_in[2];
    const float* wo_0 = (const float*)d_in[3];
    const float* bo_0 = (const float*)d_in[4];
    const float* w1_1 = (const float*)d_in[5];
    const float* b1_1 = (const float*)d_in[6];
    const float* wo_1 = (const float*)d_in[7];
    const float* bo_1 = (const float*)d_in[8];
    const float* w1_2 = (const float*)d_in[9];
    const float* b1_2 = (const float*)d_in[10];
    const float* wo_2 = (const float*)d_in[11];
    const float* bo_2 = (const float*)d_in[12];
    const float* fw1  = (const float*)d_in[13];
    const float* fb1  = (const float*)d_in[14];
    const float* fw2  = (const float*)d_in[15];
    const float* fb2  = (const float*)d_in[16];
    float* out = (float*)d_out;

    // workspace layout (floats)
    float* featA = (float*)d_ws;
    float* featB = featA + (long)BN * HH;
    float* Pb    = featB + (long)BN * HH;
    float* Qb    = Pb + (long)BN * HH;
    float* sqA   = Qb + (long)BN * HH;
    float* sqB   = sqA + BN;
    unsigned short* idx32 = (unsigned short*)(sqB + BN);     // BN x 32 u16
    float* ppb   = (float*)(idx32 + (long)BN * 32);          // 8192 x 64

    // ---- layer 0 (D=3, exact fp32 kNN; filter + prep packed) ----
    pack3_kernel<<<1024 + BN / 4, 256, 0, stream>>>(x, w1_0, b1_0, Pb, Qb, idx32);
    rescore3_kernel<<<BN / 8, 256, 0, stream>>>(x, idx32, Pb, Qb, wo_0, bo_0, featA, sqB);

    // ---- layer 1 ----
    prep_pq64_kernel<<<BN / 64, 256, 0, stream>>>(featA, w1_1, b1_1, Pb, Qb);
    knn_filter_kernel<<<BB * 32, 256, 0, stream>>>(featA, sqB, idx32);
    rescore64_kernel<false><<<BN / 8, 256, 0, stream>>>(featA, sqB, idx32, Pb, Qb, wo_1, bo_1,
                                                        featB, sqA, nullptr);

    // ---- layer 2 ----
    prep_pq64_kernel<<<BN / 64, 256, 0, stream>>>(featB, w1_2, b1_2, Pb, Qb);
    knn_filter_kernel<<<BB * 32, 256, 0, stream>>>(featB, sqA, idx32);
    rescore64_kernel<true><<<BN / 8, 256, 0, stream>>>(featB, sqA, idx32, Pb, Qb, wo_2, bo_2,
                                                       nullptr, nullptr, ppb);

    // ---- head ----
    head_kernel<<<BB, 256, 0, stream>>>(ppb, fw1, fb1, fw2, fb2, out);
}

// Round 12
// 619.179 us; speedup vs baseline: 1.0812x; 1.0812x over previous
//
#include <hip/hip_runtime.h>

// Problem constants
#define BB 32
#define NN 2048
#define FF 3
#define HH 64
#define OUTC 128
#define KK 16
#define BN (BB * NN)   // 65536 points

typedef __attribute__((ext_vector_type(8))) __bf16 bf16x8;
typedef __attribute__((ext_vector_type(4))) float f32x4;

// Pack d2 + candidate index into one sortable u32:
// high 21 bits = monotone(float d2) truncated, low 11 bits = idx (NN=2^11).
__device__ __forceinline__ unsigned int packkey(float d2, unsigned int m) {
    unsigned int bb = __builtin_bit_cast(unsigned int, d2);
    unsigned int msk = (unsigned int)((int)bb >> 31);
    unsigned int srt = bb ^ (msk | 0x80000000u);
    return (srt & 0xFFFFF800u) | m;
}

__device__ __forceinline__ void ce(unsigned int& a, unsigned int& b) {
    unsigned int lo = a < b ? a : b;
    unsigned int hi = a < b ? b : a;
    a = lo; b = hi;
}

// Sort 16 keys ascending — Batcher odd-even mergesort (63 CE, branchless).
__device__ __forceinline__ void sort16(unsigned int k[16]) {
#pragma unroll
    for (int p = 1; p < 16; p <<= 1)
#pragma unroll
        for (int q = p; q >= 1; q >>= 1)
#pragma unroll
            for (int j = q % p; j + q < 16; j += 2 * q)
#pragma unroll
                for (int i = 0; i < q; ++i) {
                    int x = i + j, y = i + j + q;
                    if (y < 16 && (x / (2 * p) == y / (2 * p))) ce(k[x], k[y]);
                }
}

// keys (sorted asc) <- lowest-16 of union(keys, nk), nk sorted asc.
__device__ __forceinline__ void merge16(unsigned int keys[16], const unsigned int nk[16]) {
    unsigned int t[16];
#pragma unroll
    for (int i = 0; i < 16; ++i) {
        unsigned int b = nk[15 - i];
        t[i] = keys[i] < b ? keys[i] : b;
    }
#pragma unroll
    for (int d = 8; d >= 1; d >>= 1)
#pragma unroll
        for (int i = 0; i < 16; ++i)
            if ((i & d) == 0) ce(t[i], t[i ^ d]);
#pragma unroll
    for (int i = 0; i < 16; ++i) keys[i] = t[i];
}

__device__ __forceinline__ unsigned short bfbits(float v) {
    return __builtin_bit_cast(unsigned short, (__bf16)v);
}

// ---------------------------------------------------------------------------
// pack3: blocks [0,1024) = layer-0 kNN filter (D=3, candidate sq inline);
//        blocks [1024, 1024+BN/4) = prep3 (P/Q GEMM for layer 0).
// ---------------------------------------------------------------------------
__global__ __launch_bounds__(256) void pack3_kernel(const float* __restrict__ x,
                                                    const float* __restrict__ w1,
                                                    const float* __restrict__ b1,
                                                    float* __restrict__ P,
                                                    float* __restrict__ Q,
                                                    unsigned short* __restrict__ idx32) {
    __shared__ float4 lds_c[256];
    __shared__ unsigned int Km[64 * 68];
    const int tid = threadIdx.x;

    if (blockIdx.x >= 1024) {
        // ---- prep3: P/Q for 4 rows ----
        const int h = tid & 63;
        const int pl = tid >> 6;
        const long p = (long)(blockIdx.x - 1024) * 4 + pl;
        const float* fp = x + p * 3;
        const float fv[3] = {fp[0], fp[1], fp[2]};
        float accp = 0.f, accq = 0.f;
#pragma unroll
        for (int d = 0; d < 3; ++d) {
            float wa = w1[d * HH + h];
            float wb = w1[(3 + d) * HH + h];
            accp = fmaf(fv[d], wa - wb, accp);
            accq = fmaf(fv[d], wb, accq);
        }
        P[p * HH + h] = accp + b1[h];
        Q[p * HH + h] = accq;
        return;
    }

    // ---- filter3: 64 rows x 2048 cands, XCD-pinned ----
    const int xcd = blockIdx.x & 7;
    const int ii = blockIdx.x >> 3;
    const int b = xcd + 8 * (ii >> 5);
    const int rg = ii & 31;
    const long pbase = (long)b * NN;
    const int r = tid >> 2, slot = tid & 3;
    const int row = rg * 64 + r;

    const float* rp = x + (pbase + row) * 3;
    const float xr0 = rp[0], xr1 = rp[1], xr2 = rp[2];

    unsigned int keys[KK];
#pragma unroll
    for (int j = 0; j < KK; ++j) keys[j] = 0xFFFFFFFFu;

    // preload tile 0 (sq inline)
    float c0, c1, c2, c3;
    {
        const float* cp = x + (pbase + tid) * 3;
        c0 = cp[0]; c1 = cp[1]; c2 = cp[2];
        c3 = c0 * c0 + c1 * c1 + c2 * c2;
    }

    for (int t = 0; t < NN / 256; ++t) {
        __syncthreads();
        lds_c[tid] = make_float4(c0, c1, c2, c3);
        __syncthreads();
        if (t < NN / 256 - 1) {
            const int m = (t + 1) * 256 + tid;
            const float* cp = x + (pbase + m) * 3;
            c0 = cp[0]; c1 = cp[1]; c2 = cp[2];
            c3 = c0 * c0 + c1 * c1 + c2 * c2;
        }
        const int cbase = slot * 64;
#pragma unroll
        for (int bb = 0; bb < 4; ++bb) {
            unsigned int nk[16];
#pragma unroll
            for (int cc = 0; cc < 16; ++cc) {
                float4 v = lds_c[cbase + bb * 16 + cc];
                float dot = fmaf(xr0, v.x, fmaf(xr1, v.y, xr2 * v.z));
                float d2 = fmaf(-2.0f, dot, v.w);   // row sq dropped (rank-invariant)
                nk[cc] = packkey(d2, (unsigned int)(t * 256 + cbase + bb * 16 + cc));
            }
            sort16(nk);
            merge16(keys, nk);
        }
    }

    {
        uint4* kw = (uint4*)&Km[r * 68 + slot * 16];
#pragma unroll
        for (int q = 0; q < 4; ++q)
            kw[q] = make_uint4(keys[4 * q], keys[4 * q + 1], keys[4 * q + 2], keys[4 * q + 3]);
    }
    __syncthreads();
    if (slot < 2) {
        const unsigned int* k0 = &Km[r * 68 + slot * 32];
        const unsigned int* k1 = k0 + 16;
        unsigned short ms[16];
#pragma unroll
        for (int j = 0; j < 16; ++j) {
            unsigned int a = k0[j], bv = k1[15 - j];
            ms[j] = (unsigned short)((a < bv ? a : bv) & 0x7FFu);
        }
        uint4* op = (uint4*)(idx32 + ((pbase + row) * 32 + slot * 16));
        op[0] = ((const uint4*)ms)[0];
        op[1] = ((const uint4*)ms)[1];
    }
}

// ---------------------------------------------------------------------------
// prep_pq64: P/Q GEMM (+ optional sq). Block = 64 rows; weights in VGPRs;
// rows via LDS broadcast ds_read_b128; split accumulators.
// ---------------------------------------------------------------------------
__global__ __launch_bounds__(256) void prep_pq64_kernel(const float* __restrict__ feat,
                                                        const float* __restrict__ w1,
                                                        const float* __restrict__ b1,
                                                        float* __restrict__ P,
                                                        float* __restrict__ Q,
                                                        float* __restrict__ sqo) {
    __shared__ float rows[64 * HH];   // 16 KB
    const int tid = threadIdx.x;
    const int h = tid & 63;
    const int wv = tid >> 6;
    const long row0 = (long)blockIdx.x * 64;

    float wdiff[64], wbv[64];
#pragma unroll
    for (int d = 0; d < 64; ++d) {
        float wa = w1[d * HH + h];
        float wb_ = w1[(HH + d) * HH + h];
        wdiff[d] = wa - wb_;
        wbv[d] = wb_;
    }
    const float bv = b1[h];

    {
        const float4* src = (const float4*)(feat + row0 * HH);
        float4* dst = (float4*)rows;
#pragma unroll
        for (int i = 0; i < 4; ++i) dst[tid + 256 * i] = src[tid + 256 * i];
    }
    __syncthreads();

    for (int r = wv * 16; r < wv * 16 + 16; ++r) {
        const long p = row0 + r;
        if (sqo) {
            float fvh = rows[r * HH + h];
            float s = fvh * fvh;
            s += __shfl_xor(s, 1);
            s += __shfl_xor(s, 2);
            s += __shfl_xor(s, 4);
            s += __shfl_xor(s, 8);
            s += __shfl_xor(s, 16);
            s += __shfl_xor(s, 32);
            if (h == 0) sqo[p] = s;
        }
        float ap0 = 0.f, ap1 = 0.f, aq0 = 0.f, aq1 = 0.f;
#pragma unroll
        for (int d4 = 0; d4 < 16; ++d4) {
            float4 fv = *(const float4*)&rows[r * HH + d4 * 4];   // uniform -> broadcast
            ap0 = fmaf(fv.x, wdiff[4 * d4 + 0], ap0);
            aq0 = fmaf(fv.x, wbv[4 * d4 + 0], aq0);
            ap1 = fmaf(fv.y, wdiff[4 * d4 + 1], ap1);
            aq1 = fmaf(fv.y, wbv[4 * d4 + 1], aq1);
            ap0 = fmaf(fv.z, wdiff[4 * d4 + 2], ap0);
            aq0 = fmaf(fv.z, wbv[4 * d4 + 2], aq0);
            ap1 = fmaf(fv.w, wdiff[4 * d4 + 3], ap1);
            aq1 = fmaf(fv.w, wbv[4 * d4 + 3], aq1);
        }
        P[p * HH + h] = (ap0 + ap1) + bv;
        Q[p * HH + h] = aq0 + aq1;
    }
}

// ---------------------------------------------------------------------------
// bf16-MFMA filter (D=64): fp32 staging with inline bf16 convert. Register
// prefetch, XCD-pinned batches, u16 output.
// ---------------------------------------------------------------------------
#define APAD 80   // LDS row stride (bf16 elems)
#define DPAD 68   // key-tile stride (u32)

__global__ __launch_bounds__(256) void knn_filter_kernel(const float* __restrict__ feat,
                                                         const float* __restrict__ sq,
                                                         unsigned short* __restrict__ idx32) {
    __shared__ __align__(16) __bf16 Ab[64 * APAD];
    __shared__ __align__(16) __bf16 Bb[64 * APAD];
    __shared__ __align__(16) unsigned int Dt[64 * DPAD];
    __shared__ float SqC[64];

    const int tid = threadIdx.x;
    const int xcd = blockIdx.x & 7;
    const int ii = blockIdx.x >> 3;
    const int b = xcd + 8 * (ii >> 5);
    const int rg = ii & 31;
    const long pbase = (long)b * NN;
    const int row0 = rg * 64;

    // stage A (64 rows x 64 dims): fp32 load -> bf16 LDS
    {
        const float4* src = (const float4*)(feat + (pbase + row0) * 64);
#pragma unroll
        for (int it = 0; it < 4; ++it) {
            const int i = it * 256 + tid;
            float4 v = src[i];
            const int rw = i >> 4, col = (i & 15) * 4;
            unsigned short u[4] = {bfbits(v.x), bfbits(v.y), bfbits(v.z), bfbits(v.w)};
            *(uint2*)&Ab[rw * APAD + col] = *(const uint2*)u;
        }
    }
    __syncthreads();

    const int wv = tid >> 6, ln = tid & 63;
    const int n16 = ln & 15, quad = ln >> 4;
    bf16x8 af0, af1;
    {
        const __bf16* ap = &Ab[(wv * 16 + n16) * APAD + quad * 8];
        af0 = *(const bf16x8*)ap;
        af1 = *(const bf16x8*)(ap + 32);
    }

    const int r = tid >> 2, slot = tid & 3;
    unsigned int keys[KK];
#pragma unroll
    for (int j = 0; j < KK; ++j) keys[j] = 0xFFFFFFFFu;

    // preload tile 0 into registers
    float4 pv[4];
    float psq;
    {
        const float4* src = (const float4*)(feat + pbase * 64);
#pragma unroll
        for (int it = 0; it < 4; ++it) pv[it] = src[it * 256 + tid];
        psq = (tid < 64) ? sq[pbase + tid] : 0.f;
    }

    for (int t = 0; t < NN / 64; ++t) {
        // staged write (registers -> bf16 LDS)
#pragma unroll
        for (int it = 0; it < 4; ++it) {
            const int i = it * 256 + tid;
            const int rw = i >> 4, col = (i & 15) * 4;
            unsigned short u[4] = {bfbits(pv[it].x), bfbits(pv[it].y),
                                   bfbits(pv[it].z), bfbits(pv[it].w)};
            *(uint2*)&Bb[rw * APAD + col] = *(const uint2*)u;
        }
        if (tid < 64) SqC[tid] = psq;
        __syncthreads();   // barrier 1: Bb/SqC ready; prev selection done with Dt

        // MFMA phase
#pragma unroll
        for (int ct = 0; ct < 4; ++ct) {
            const __bf16* bp = &Bb[(ct * 16 + n16) * APAD + quad * 8];
            bf16x8 bf0 = *(const bf16x8*)bp;
            bf16x8 bf1 = *(const bf16x8*)(bp + 32);
            f32x4 acc = {0.f, 0.f, 0.f, 0.f};
            acc = __builtin_amdgcn_mfma_f32_16x16x32_bf16(af0, bf0, acc, 0, 0, 0);
            acc = __builtin_amdgcn_mfma_f32_16x16x32_bf16(af1, bf1, acc, 0, 0, 0);
            const int ccol = ct * 16 + n16;
            const float sqc = SqC[ccol];
            const unsigned int m = (unsigned int)(t * 64 + ccol);
#pragma unroll
            for (int rr = 0; rr < 4; ++rr) {
                const int rrow = wv * 16 + quad * 4 + rr;
                Dt[rrow * DPAD + ccol] = packkey(fmaf(-2.0f, acc[rr], sqc), m);
            }
        }
        __syncthreads();   // barrier 2: Dt ready, Bb reads done

        // prefetch next tile (hidden by selection)
        if (t < NN / 64 - 1) {
            const float4* src = (const float4*)(feat + (pbase + (long)(t + 1) * 64) * 64);
#pragma unroll
            for (int it = 0; it < 4; ++it) pv[it] = src[it * 256 + tid];
            if (tid < 64) psq = sq[pbase + (t + 1) * 64 + tid];
        }

        // selection
        {
            const uint4* kp = (const uint4*)&Dt[r * DPAD + slot * 16];
            unsigned int nk[16];
#pragma unroll
            for (int q = 0; q < 4; ++q) {
                uint4 kv = kp[q];
                nk[4 * q + 0] = kv.x; nk[4 * q + 1] = kv.y;
                nk[4 * q + 2] = kv.z; nk[4 * q + 3] = kv.w;
            }
            sort16(nk);
            merge16(keys, nk);
        }
    }

    __syncthreads();
    {
        uint4* kw = (uint4*)&Dt[r * DPAD + slot * 16];
#pragma unroll
        for (int q = 0; q < 4; ++q)
            kw[q] = make_uint4(keys[4 * q], keys[4 * q + 1], keys[4 * q + 2], keys[4 * q + 3]);
    }
    __syncthreads();
    if (slot < 2) {
        const unsigned int* k0 = &Dt[r * DPAD + slot * 32];
        const unsigned int* k1 = k0 + 16;
        unsigned short ms[16];
#pragma unroll
        for (int j = 0; j < 16; ++j) {
            unsigned int a = k0[j], bv = k1[15 - j];
            ms[j] = (unsigned short)((a < bv ? a : bv) & 0x7FFu);
        }
        uint4* op = (uint4*)(idx32 + ((pbase + row0 + r) * 32 + slot * 16));
        op[0] = ((const uint4*)ms)[0];
        op[1] = ((const uint4*)ms)[1];
    }
}

// ---------------------------------------------------------------------------
// rescore3: exact fp32 rescore (cand sq inline) + gather + MLP0 -> featA;
// tail writes layer-1 sq (cheap here — this kernel is small). Block = 8 rows.
// ---------------------------------------------------------------------------
__global__ __launch_bounds__(256) void rescore3_kernel(const float* __restrict__ x,
                                                       const unsigned short* __restrict__ idx32,
                                                       const float* __restrict__ P,
                                                       const float* __restrict__ Q,
                                                       const float* __restrict__ wo,
                                                       const float* __restrict__ bo,
                                                       float* __restrict__ outf,
                                                       float* __restrict__ sqn) {
    __shared__ float rowf[8][3];
    __shared__ float Sc[8][32];
    __shared__ int Ji[8][32];
    __shared__ int Li[8][KK];
    __shared__ float Rl[8][HH];
    const int tid = threadIdx.x;
    const int w = tid >> 6, ln = tid & 63;
    const int rw = ln >> 5, c = ln & 31;
    const int xcd = blockIdx.x & 7;
    const int ii = blockIdx.x >> 3;
    const int batch = xcd + 8 * (ii >> 8);
    const int rb = ii & 255;
    const long pbase = (long)batch * NN;
    const long pblk = pbase + (long)rb * 8;
    const long p = pblk + w * 2 + rw;
    const int row_ = w * 2 + rw;

    for (int i = tid; i < 24; i += 256) rowf[i / 3][i % 3] = x[pblk * 3 + i];
    Ji[row_][c] = (int)idx32[p * 32 + c];
    __syncthreads();

    {
        const int jj = Ji[row_][c];
        const float* cp = x + (pbase + jj) * 3;
        const float c0 = cp[0], c1 = cp[1], c2 = cp[2];
        const float sqc = c0 * c0 + c1 * c1 + c2 * c2;
        float dot = fmaf(rowf[row_][0], c0, fmaf(rowf[row_][1], c1, rowf[row_][2] * c2));
        Sc[row_][c] = fmaf(-2.0f, dot, sqc);
    }
    __syncthreads();

    {
        const float score = Sc[row_][c];
        const int j = Ji[row_][c];
        int rank = 0;
#pragma unroll
        for (int m = 0; m < 32; ++m) {
            float dm = Sc[row_][m];
            int jm = Ji[row_][m];
            rank += (dm < score || (dm == score && jm < j)) ? 1 : 0;
        }
        if (rank < KK) Li[row_][rank] = j;
    }
    __syncthreads();

    const int h = tid & 63, pl = tid >> 6;
#pragma unroll
    for (int rr0 = 0; rr0 < 2; ++rr0) {
        const int rr = pl + rr0 * 4;
        const long pp = pblk + rr;
        const float Pv = P[pp * HH + h];
        float acc = 0.f;
#pragma unroll
        for (int k = 0; k < KK; ++k) {
            int j2 = Li[rr][k];
            acc += fmaxf(Pv + Q[(pbase + j2) * HH + h], 0.f);
        }
        Rl[rr][h] = acc * (1.f / KK);
    }
    __syncthreads();
#pragma unroll
    for (int rr0 = 0; rr0 < 2; ++rr0) {
        const int rr = pl + rr0 * 4;
        float o = bo[h];
#pragma unroll
        for (int l = 0; l < HH; ++l) o = fmaf(Rl[rr][l], wo[l * HH + h], o);
        outf[(pblk + rr) * HH + h] = o;
        float s2 = o * o;
        s2 += __shfl_xor(s2, 1);
        s2 += __shfl_xor(s2, 2);
        s2 += __shfl_xor(s2, 4);
        s2 += __shfl_xor(s2, 8);
        s2 += __shfl_xor(s2, 16);
        s2 += __shfl_xor(s2, 32);
        if (h == 0) sqn[pblk + rr] = s2;
    }
}

// ---------------------------------------------------------------------------
// rescore64 (lean): exact fp32 rescore + gather + MLP -> outf. Block = 8 rows.
// Coalescing-optimal gather: 4 consecutive lanes share a candidate line.
// Keep this kernel latency-hiding-friendly — no fused tails (R11 regression).
// ---------------------------------------------------------------------------
__global__ __launch_bounds__(256) void rescore64_kernel(const float* __restrict__ feat,
                                                        const float* __restrict__ sq,
                                                        const unsigned short* __restrict__ idx32,
                                                        const float* __restrict__ P,
                                                        const float* __restrict__ Q,
                                                        const float* __restrict__ wo,
                                                        const float* __restrict__ bo,
                                                        float* __restrict__ outf) {
    __shared__ float rowf[8][HH];
    __shared__ float Sc[8][32];
    __shared__ int Ji[8][32];
    __shared__ float Sq32[8][32];
    __shared__ int Li[8][KK];
    __shared__ float Rl[8][HH];
    const int tid = threadIdx.x;
    const int w = tid >> 6, ln = tid & 63;
    const int rw = ln >> 5, c = ln & 31;
    const int xcd = blockIdx.x & 7;
    const int ii = blockIdx.x >> 3;
    const int batch = xcd + 8 * (ii >> 8);
    const int rb = ii & 255;
    const long pbase = (long)batch * NN;
    const long pblk = pbase + (long)rb * 8;
    const long p = pblk + w * 2 + rw;
    const int row_ = w * 2 + rw;

    for (int i = tid; i < 8 * HH; i += 256) rowf[i / HH][i % HH] = feat[pblk * HH + i];
    {
        const int j0 = (int)idx32[p * 32 + c];
        Ji[row_][c] = j0;
        Sq32[row_][c] = sq[pbase + j0];
    }
    __syncthreads();

    {
        const int cg = ln >> 2, e = ln & 3;
#pragma unroll
        for (int rr = 0; rr < 2; ++rr) {
#pragma unroll
            for (int pp = 0; pp < 2; ++pp) {
                const int row = w * 2 + rr;
                const int cand = pp * 16 + cg;
                const int jj = Ji[row][cand];
                const float* cb = feat + (pbase + jj) * 64;
                float part = 0.f;
#pragma unroll
                for (int blk = 0; blk < 4; ++blk) {
                    float4 cv = *(const float4*)(cb + blk * 16 + e * 4);
                    float4 rv = *(const float4*)&rowf[row][blk * 16 + e * 4];
                    part = fmaf(rv.x, cv.x, part);
                    part = fmaf(rv.y, cv.y, part);
                    part = fmaf(rv.z, cv.z, part);
                    part = fmaf(rv.w, cv.w, part);
                }
                part += __shfl_xor(part, 1);
                part += __shfl_xor(part, 2);
                if (e == 0) Sc[row][cand] = fmaf(-2.0f, part, Sq32[row][cand]);
            }
        }
    }
    __syncthreads();

    {
        const float score = Sc[row_][c];
        const int j = Ji[row_][c];
        int rank = 0;
#pragma unroll
        for (int m = 0; m < 32; ++m) {
            float dm = Sc[row_][m];
            int jm = Ji[row_][m];
            rank += (dm < score || (dm == score && jm < j)) ? 1 : 0;
        }
        if (rank < KK) Li[row_][rank] = j;
    }
    __syncthreads();

    const int h = tid & 63, pl = tid >> 6;
#pragma unroll
    for (int rr0 = 0; rr0 < 2; ++rr0) {
        const int rr = pl + rr0 * 4;
        const long pp = pblk + rr;
        const float Pv = P[pp * HH + h];
        float acc = 0.f;
#pragma unroll
        for (int k = 0; k < KK; ++k) {
            int j2 = Li[rr][k];
            acc += fmaxf(Pv + Q[(pbase + j2) * HH + h], 0.f);
        }
        Rl[rr][h] = acc * (1.f / KK);
    }
    __syncthreads();
#pragma unroll
    for (int rr0 = 0; rr0 < 2; ++rr0) {
        const int rr = pl + rr0 * 4;
        float o = bo[h];
#pragma unroll
        for (int l = 0; l < HH; ++l) o = fmaf(Rl[rr][l], wo[l * HH + h], o);
        outf[(pblk + rr) * HH + h] = o;
    }
}

// ---------------------------------------------------------------------------
// pool partial: block = (batch, chunk of 8); sums 256 rows -> pp[batch][ch][64]
// ---------------------------------------------------------------------------
__global__ __launch_bounds__(256) void pool_partial_kernel(const float* __restrict__ feat,
                                                           float* __restrict__ pp) {
    __shared__ float part[4][HH];
    const int batch = blockIdx.x >> 3;
    const int chk = blockIdx.x & 7;
    const int tid = threadIdx.x;
    const int h = tid & 63;
    const int sub = tid >> 6;
    float s = 0.f;
    const float* fp = feat + ((long)batch * NN + chk * 256 + sub * 64) * HH + h;
    for (int n = 0; n < 64; ++n) s += fp[(long)n * HH];
    part[sub][h] = s;
    __syncthreads();
    if (tid < HH)
        pp[(batch * 8 + chk) * HH + h] = part[0][h] + part[1][h] + part[2][h] + part[3][h];
}

// ---------------------------------------------------------------------------
// head: g[b] = mean; out[b] = relu(g@fw1+fb1)@fw2+fb2. Block = batch.
// ---------------------------------------------------------------------------
__global__ __launch_bounds__(256) void head_kernel(const float* __restrict__ pp,
                                                   const float* __restrict__ fw1,
                                                   const float* __restrict__ fb1,
                                                   const float* __restrict__ fw2,
                                                   const float* __restrict__ fb2,
                                                   float* __restrict__ out) {
    __shared__ float g[HH];
    __shared__ float tl[HH];
    const int b = blockIdx.x;
    const int tid = threadIdx.x;
    if (tid < HH) {
        float s = 0.f;
#pragma unroll
        for (int c = 0; c < 8; ++c) s += pp[(b * 8 + c) * HH + tid];
        g[tid] = s * (1.f / NN);
    }
    __syncthreads();
    if (tid < HH) {
        float a = fb1[tid];
#pragma unroll
        for (int l = 0; l < HH; ++l) a = fmaf(g[l], fw1[l * HH + tid], a);
        tl[tid] = fmaxf(a, 0.f);
    }
    __syncthreads();
    if (tid < OUTC) {
        float o = fb2[tid];
#pragma unroll
        for (int l = 0; l < HH; ++l) o = fmaf(tl[l], fw2[l * OUTC + tid], o);
        out[(long)b * OUTC + tid] = o;
    }
}

// ---------------------------------------------------------------------------
extern "C" void kernel_launch(void* const* d_in, const int* in_sizes, int n_in,
                              void* d_out, int out_size, void* d_ws, size_t ws_size,
                              hipStream_t stream) {
    const float* x    = (const float*)d_in[0];
    const float* w1_0 = (const float*)d_in[1];
    const float* b1_0 = (const float*)d_in[2];
    const float* wo_0 = (const float*)d_in[3];
    const float* bo_0 = (const float*)d_in[4];
    const float* w1_1 = (const float*)d_in[5];
    const float* b1_1 = (const float*)d_in[6];
    const float* wo_1 = (const float*)d_in[7];
    const float* bo_1 = (const float*)d_in[8];
    const float* w1_2 = (const float*)d_in[9];
    const float* b1_2 = (const float*)d_in[10];
    const float* wo_2 = (const float*)d_in[11];
    const float* bo_2 = (const float*)d_in[12];
    const float* fw1  = (const float*)d_in[13];
    const float* fb1  = (const float*)d_in[14];
    const float* fw2  = (const float*)d_in[15];
    const float* fb2  = (const float*)d_in[16];
    float* out = (float*)d_out;

    // workspace layout (floats)
    float* featA = (float*)d_ws;
    float* featB = featA + (long)BN * HH;
    float* Pb    = featB + (long)BN * HH;
    float* Qb    = Pb + (long)BN * HH;
    float* sqA   = Qb + (long)BN * HH;
    float* sqB   = sqA + BN;
    unsigned short* idx32 = (unsigned short*)(sqB + BN);     // BN x 32 u16
    float* ppb   = (float*)(idx32 + (long)BN * 32);          // 32 x 8 x 64

    // ---- layer 0 (D=3, exact fp32 kNN; filter + prep packed) ----
    pack3_kernel<<<1024 + BN / 4, 256, 0, stream>>>(x, w1_0, b1_0, Pb, Qb, idx32);
    rescore3_kernel<<<BN / 8, 256, 0, stream>>>(x, idx32, Pb, Qb, wo_0, bo_0, featA, sqB);

    // ---- layer 1 ----
    prep_pq64_kernel<<<BN / 64, 256, 0, stream>>>(featA, w1_1, b1_1, Pb, Qb, nullptr);
    knn_filter_kernel<<<BB * 32, 256, 0, stream>>>(featA, sqB, idx32);
    rescore64_kernel<<<BN / 8, 256, 0, stream>>>(featA, sqB, idx32, Pb, Qb, wo_1, bo_1, featB);

    // ---- layer 2 ----
    prep_pq64_kernel<<<BN / 64, 256, 0, stream>>>(featB, w1_2, b1_2, Pb, Qb, sqA);
    knn_filter_kernel<<<BB * 32, 256, 0, stream>>>(featB, sqA, idx32);
    rescore64_kernel<<<BN / 8, 256, 0, stream>>>(featB, sqA, idx32, Pb, Qb, wo_2, bo_2, featA);

    // ---- pool + head ----
    pool_partial_kernel<<<BB * 8, 256, 0, stream>>>(featA, ppb);
    head_kernel<<<BB, 256, 0, stream>>>(ppb, fw1, fb1, fw2, fb2, out);
}